// Round 1
// baseline (109.576 us; speedup 1.0000x reference)
//
#include <hip/hip_runtime.h>

#define IMG_W 256
#define IMG_H 256
#define N_PTS 320
#define VD 256
#define VH 256
#define VW 256
#define DSTEP (6.0f / (N_PTS - 1))
#define RPB 16   // rays per render block (along w)
#define CPR 16   // chunk-threads per ray
#define NBLK ((IMG_W / RPB) * IMG_H)   // 4096 render blocks

// ws layout (float*): [0..NBLK) = per-render-block gray max (written unconditionally,
// so the poisoned workspace never needs a clearing memset)

struct RayCoef { float fAx, fBx, fAy, fBy, fAz, fBz; };

__device__ __forceinline__ RayCoef ray_coef(int w, int h,
                                            const float* __restrict__ Rm,
                                            const float* __restrict__ Tv,
                                            const float* __restrict__ focal) {
    const float a  = 1.0f - 1.0f / IMG_W;
    const float gx = a - (2.0f * a / (IMG_W - 1)) * (float)w;
    const float gy = a - (2.0f * a / (IMG_H - 1)) * (float)h;
    const float f  = focal[0];
    const float ux = gx / f, uy = gy / f;
    const float R00 = Rm[0], R01 = Rm[1], R02 = Rm[2];
    const float R10 = Rm[3], R11 = Rm[4], R12 = Rm[5];
    const float R20 = Rm[6], R21 = Rm[7], R22 = Rm[8];
    const float Tx = Tv[0], Ty = Tv[1], Tz = Tv[2];
    const float Bx = R00 * ux + R01 * uy + R02;
    const float By = R10 * ux + R11 * uy + R12;
    const float Bz = R20 * ux + R21 * uy + R22;
    const float Ax = -(R00 * Tx + R01 * Ty + R02 * Tz);
    const float Ay = -(R10 * Tx + R11 * Ty + R12 * Tz);
    const float Az = -(R20 * Tx + R21 * Ty + R22 * Tz);
    const float voxel = 2.0f / 256.0f;
    const float hx = voxel * (VW - 1) * 0.5f;
    const float hy = voxel * (VH - 1) * 0.5f;
    const float hz = voxel * (VD - 1) * 0.5f;
    const float sxc = 0.5f * (VW - 1) / hx, oxc = 0.5f * (VW - 1);
    const float syc = 0.5f * (VH - 1) / hy, oyc = 0.5f * (VH - 1);
    const float szc = 0.5f * (VD - 1) / hz, ozc = 0.5f * (VD - 1);
    RayCoef rc;
    rc.fBx = Bx * sxc; rc.fAx = Ax * sxc + oxc;
    rc.fBy = By * syc; rc.fAy = Ay * syc + oyc;
    rc.fBz = Bz * szc; rc.fAz = Az * szc + ozc;
    return rc;
}

// exact sample range [pmin, pmin+len) outside of which dens == feat == 0
__device__ __forceinline__ void clip_ray(const RayCoef& rc, int& pmin, int& len) {
    float dlo = 3.0f, dhi = 9.0f;
    const float lo = -1.0f, hi = 256.0f;
    const float fA[3] = { rc.fAx, rc.fAy, rc.fAz };
    const float fB[3] = { rc.fBx, rc.fBy, rc.fBz };
    #pragma unroll
    for (int dim = 0; dim < 3; ++dim) {
        if (fabsf(fB[dim]) > 1e-12f) {
            const float r = 1.0f / fB[dim];
            const float t0 = (lo - fA[dim]) * r, t1 = (hi - fA[dim]) * r;
            dlo = fmaxf(dlo, fminf(t0, t1));
            dhi = fminf(dhi, fmaxf(t0, t1));
        } else if (fA[dim] < lo || fA[dim] >= hi) {
            dhi = -1.0f;
        }
    }
    pmin = 0; len = 0;
    if (dhi > dlo) {
        pmin = max(0, (int)floorf((dlo - 3.0f) / DSTEP) - 1);
        int pmax = min(N_PTS, (int)ceilf((dhi - 3.0f) / DSTEP) + 2);
        len = max(0, pmax - pmin);
    }
}

// fused: each block statically owns rays [blockIdx.x*RPB .. +16) of row h=blockIdx.y.
// Inactive rays fall through with len=0 and produce gray==0 exactly (as prep did).
__global__ __launch_bounds__(256) void render_kernel(
    const float* __restrict__ vol, const float* __restrict__ Rm,
    const float* __restrict__ Tv, const float* __restrict__ focal,
    float* __restrict__ out, float* __restrict__ wsf)
{
    const int tx = threadIdx.x;              // ray slot 0..15
    const int ty = threadIdx.y;              // chunk    0..15
    const int w = blockIdx.x * RPB + tx;
    const int h = blockIdx.y;

    const RayCoef rc = ray_coef(w, h, Rm, Tv, focal);
    int pmin, len;
    clip_ray(rc, pmin, len);

    const int plo = pmin + ((len * ty) >> 4);
    const int phi = pmin + ((len * (ty + 1)) >> 4);

    float S = 0.0f, A = 1.0f;
    for (int p = plo; p < phi; ++p) {
        const float d = 3.0f + (float)p * DSTEP;
        const float fx = fmaf(rc.fBx, d, rc.fAx);
        const float fy = fmaf(rc.fBy, d, rc.fAy);
        const float fz = fmaf(rc.fBz, d, rc.fAz);

        const float flx = floorf(fx), fly = floorf(fy), flz = floorf(fz);
        const int ix0 = (int)flx, iy0 = (int)fly, iz0 = (int)flz;

        float dens = 0.0f, feat = 0.0f;
        if (ix0 >= -1 && ix0 < VW && iy0 >= -1 && iy0 < VH && iz0 >= -1 && iz0 < VD) {
            const float frx = fx - flx, fry = fy - fly, frz = fz - flz;
            float wx0 = 1.0f - frx, wx1 = frx;
            float wy0 = 1.0f - fry, wy1 = fry;
            float wz0 = 1.0f - frz, wz1 = frz;
            if (ix0 < 0)       wx0 = 0.0f;
            if (ix0 + 1 >= VW) wx1 = 0.0f;
            if (iy0 < 0)       wy0 = 0.0f;
            if (iy0 + 1 >= VH) wy1 = 0.0f;
            if (iz0 < 0)       wz0 = 0.0f;
            if (iz0 + 1 >= VD) wz1 = 0.0f;

            const int cx0 = max(ix0, 0), cx1 = min(ix0 + 1, VW - 1);
            const int cy0 = max(iy0, 0), cy1 = min(iy0 + 1, VH - 1);
            const int cz0 = max(iz0, 0), cz1 = min(iz0 + 1, VD - 1);

            const int zb0 = cz0 * (VH * VW), zb1 = cz1 * (VH * VW);
            const int yb0 = cy0 * VW,        yb1 = cy1 * VW;

            const float v000 = vol[zb0 + yb0 + cx0];
            const float v001 = vol[zb0 + yb0 + cx1];
            const float v010 = vol[zb0 + yb1 + cx0];
            const float v011 = vol[zb0 + yb1 + cx1];
            const float v100 = vol[zb1 + yb0 + cx0];
            const float v101 = vol[zb1 + yb0 + cx1];
            const float v110 = vol[zb1 + yb1 + cx0];
            const float v111 = vol[zb1 + yb1 + cx1];

            const float w00 = wy0 * wz0, w01 = wy1 * wz0;
            const float w10 = wy0 * wz1, w11 = wy1 * wz1;
            const float c000 = wx0 * w00, c001 = wx1 * w00;
            const float c010 = wx0 * w01, c011 = wx1 * w01;
            const float c100 = wx0 * w10, c101 = wx1 * w10;
            const float c110 = wx0 * w11, c111 = wx1 * w11;

            feat = c000 * v000 + c001 * v001 + c010 * v010 + c011 * v011
                 + c100 * v100 + c101 * v101 + c110 * v110 + c111 * v111;
            dens = 0.1f * (c000 + c001 + c010 + c011 + c100 + c101 + c110 + c111);
        }

        S = fmaf(dens * A, feat, S);   // (1 + 1e-10) rounds to 1.0f
        A *= (1.0f - dens);
    }

    __shared__ float lS[CPR][RPB];
    __shared__ float lA[CPR][RPB];
    lS[ty][tx] = S;
    lA[ty][tx] = A;
    __syncthreads();

    if (ty == 0) {
        float Stot = 0.0f, Atot = 1.0f;
        #pragma unroll
        for (int c = 0; c < CPR; ++c) {
            Stot = fmaf(Atot, lS[c][tx], Stot);
            Atot *= lA[c][tx];
        }
        const float gray = (3.0f * Stot + (1.0f - Atot)) * 0.25f;
        out[w * IMG_H + h] = gray;     // inactive rays: S=0, A=1 -> gray = 0 exactly

        // block max over the 16 ty==0 lanes (lanes >=16 never reach lane 0:
        // step 8 contaminates lanes 8..15 only; steps 4/2/1 read lanes <8)
        float m = gray;                // gray >= 0 always (vol >= 0)
        m = fmaxf(m, __shfl_down(m, 8));
        m = fmaxf(m, __shfl_down(m, 4));
        m = fmaxf(m, __shfl_down(m, 2));
        m = fmaxf(m, __shfl_down(m, 1));
        if (tx == 0)
            wsf[blockIdx.y * (IMG_W / RPB) + blockIdx.x] = m;  // unconditional: overwrites poison
    }
}

// reduce the 4096 per-block maxes (16 KB, L2-hot) redundantly per block, then scale
__global__ __launch_bounds__(256) void normalize_kernel(
    float* __restrict__ out, const float* __restrict__ wsf)
{
    __shared__ float smax[4];
    const int t = threadIdx.x;

    float m = 0.0f;
    const float4* v4 = (const float4*)wsf;        // 4096 floats = 1024 float4
    #pragma unroll
    for (int k = 0; k < 4; ++k) {
        const float4 v = v4[t + 256 * k];
        m = fmaxf(m, fmaxf(fmaxf(v.x, v.y), fmaxf(v.z, v.w)));
    }
    m = fmaxf(m, __shfl_down(m, 32));
    m = fmaxf(m, __shfl_down(m, 16));
    m = fmaxf(m, __shfl_down(m, 8));
    m = fmaxf(m, __shfl_down(m, 4));
    m = fmaxf(m, __shfl_down(m, 2));
    m = fmaxf(m, __shfl_down(m, 1));
    if ((t & 63) == 0) smax[t >> 6] = m;
    __syncthreads();
    const float mm = fmaxf(fmaxf(smax[0], smax[1]), fmaxf(smax[2], smax[3]));

    const int i = blockIdx.x * 256 + t;
    out[i] = (out[i] + 1e-8f) / (mm + 1e-8f);
}

extern "C" void kernel_launch(void* const* d_in, const int* in_sizes, int n_in,
                              void* d_out, int out_size, void* d_ws, size_t ws_size,
                              hipStream_t stream) {
    (void)in_sizes; (void)n_in; (void)out_size; (void)ws_size;
    const float* vol   = (const float*)d_in[0];
    const float* Rm    = (const float*)d_in[1];
    const float* Tv    = (const float*)d_in[2];
    const float* focal = (const float*)d_in[3];
    float* out = (float*)d_out;
    float* wsf = (float*)d_ws;

    dim3 rblock(RPB, CPR, 1);
    dim3 rgrid(IMG_W / RPB, IMG_H, 1);
    render_kernel<<<rgrid, rblock, 0, stream>>>(vol, Rm, Tv, focal, out, wsf);

    normalize_kernel<<<(IMG_W * IMG_H) / 256, 256, 0, stream>>>(out, wsf);
}